// Round 13
// baseline (309.552 us; speedup 1.0000x reference)
//
#include <hip/hip_runtime.h>
#include <hip/hip_bf16.h>
#include <stdint.h>

#define B    4096
#define NU   20000
#define NI   10000
#define RS   10001   // interactions row stride (ints)
#define XAS  320     // Xall row stride in dwords (10240 bits; 10000 used)
#define XTS  640     // XallT row stride in dwords (20480 bits; 20000 used)
#define NKI  625     // item K dwords (20000 bits)
#define NKU  313     // user K dwords (10000+16 pad bits)
#define SPI  32      // item split-K segments (kch 20)
#define SPU  16      // user split-K segments (kch 20)
#define KCH  20
#define NGRP 97667   // ceil(ceil(20000*10001/256)/8) 8-chunk groups

typedef __attribute__((ext_vector_type(8))) short bf16x8;
typedef __attribute__((ext_vector_type(4))) float f32x4;

// ---------- A: flat-front bit pack, store-decoupled.
// Per wave-group: 8 fully-unrolled 1KB uint4 loads (8KB contiguous run, MLP=8),
// nibble+shfl merge -> LDS 64-word tile -> ONE 256B full-wave store. ----------
__global__ __launch_bounds__(256) void k_packflat(const int* __restrict__ X,
                                                  uint32_t* __restrict__ Xflat) {
  __shared__ uint32_t buf[4][64];
  int wid = threadIdx.x >> 6, lane = threadIdx.x & 63;
  int wg = blockIdx.x * 4 + wid;               // 0..4095
  const uint4* Xv = (const uint4*)X;           // X base 16B-aligned
  for (int g0 = wg; g0 < NGRP; g0 += 4096) {
    size_t c0 = (size_t)g0 * 8;
#pragma unroll
    for (int i = 0; i < 8; ++i) {
      uint4 v = Xv[(c0 + i) * 64 + lane];      // tail overrun lands in X's spare row
      uint32_t nib = (v.x ? 1u : 0u) | (v.y ? 2u : 0u) | (v.z ? 4u : 0u) | (v.w ? 8u : 0u);
      uint32_t acc = nib << ((lane & 7) * 4);
      acc |= __shfl_xor(acc, 1);
      acc |= __shfl_xor(acc, 2);
      acc |= __shfl_xor(acc, 4);               // lanes 8g..8g+7 hold word g
      if ((lane & 7) == 0) buf[wid][i * 8 + (lane >> 3)] = acc;
    }
    Xflat[c0 * 8 + lane] = buf[wid][lane];     // 256B coalesced, full lines
  }
}

// ---------- B: realign flat bits to row-aligned Xall words (funnel shift/row) ----------
__global__ __launch_bounds__(256) void k_realign(const uint32_t* __restrict__ Xflat,
                                                 uint32_t* __restrict__ Xall) {
  int gid = blockIdx.x * 256 + threadIdx.x;    // u*320 + k, 6.4M total
  int u = gid / 320;
  int k = gid - u * 320;
  uint32_t val = 0;
  if (k < 313) {
    size_t a = (size_t)u * RS;                 // flat element base of row u
    size_t W0 = (a >> 5) + k;
    int s = (int)(a & 31);
    uint32_t lo = Xflat[W0];
    uint32_t hi = Xflat[W0 + 1];
    val = s ? ((lo >> s) | (hi << (32 - s))) : lo;
    if (k == 312) val &= 0xFFFFu;              // cols 9984..9999 only
  }
  Xall[gid] = val;
}

// ---------- P2: bit transpose via register butterfly, coalesced via LDS ----------
__global__ __launch_bounds__(256) void k_bitT(const uint32_t* __restrict__ Xall,
                                              uint32_t* __restrict__ XallT) {
  __shared__ uint32_t ilo[512][9], ihi[512][9];   // odd stride -> conflict-free cols
  __shared__ uint32_t olo[512][9], ohi[512][9];
  int t = threadIdx.x;
  int lane = t & 63, wd = t >> 6;
  int W0 = blockIdx.x * 8;                   // u64-word group along j
  int u0 = blockIdx.y * 512;                 // u band
  int rr = t >> 3, w = t & 7;
  const unsigned long long* Xq = (const unsigned long long*)Xall;
  unsigned long long* Tq = (unsigned long long*)XallT;
  for (int i = 0; i < 16; ++i) {
    int r = rr + 32 * i;
    int u = u0 + r;
    unsigned long long v = (u < NU) ? Xq[(size_t)u * (XAS / 2) + W0 + w] : 0ULL;
    ilo[r][w] = (uint32_t)v;
    ihi[r][w] = (uint32_t)(v >> 32);
  }
  __syncthreads();
  const unsigned long long ML[6] = {
    0x5555555555555555ULL, 0x3333333333333333ULL, 0x0F0F0F0F0F0F0F0FULL,
    0x00FF00FF00FF00FFULL, 0x0000FFFF0000FFFFULL, 0x00000000FFFFFFFFULL };
  for (int i = 0; i < 16; ++i) {
    int tile = wd * 16 + i;
    int c = tile >> 3, W = tile & 7;
    int rowi = c * 64 + lane;
    unsigned long long x = ((unsigned long long)ihi[rowi][W] << 32) | ilo[rowi][W];
#pragma unroll
    for (int lv = 0; lv < 6; ++lv) {
      int s = 1 << lv;
      unsigned long long m = ML[lv];
      uint32_t xl = (uint32_t)x, xh = (uint32_t)(x >> 32);
      unsigned long long y = ((unsigned long long)__shfl_xor(xh, s) << 32) |
                             (uint32_t)__shfl_xor(xl, s);
      x = (lane & s) ? ((x & ~m) | ((y & ~m) >> s))
                     : ((x & m) | ((y & m) << s));
    }
    int rowo = W * 64 + lane;
    olo[rowo][c] = (uint32_t)x;
    ohi[rowo][c] = (uint32_t)(x >> 32);
  }
  __syncthreads();
  for (int i = 0; i < 16; ++i) {
    int r = rr + 32 * i;
    int j = W0 * 64 + r;
    unsigned long long v = ((unsigned long long)ohi[r][w] << 32) | olo[r][w];
    Tq[(size_t)j * (XTS / 2) + blockIdx.y * 8 + w] = v;
  }
}

// ---------- W: both weights -> per-lane-contiguous bf16 fragment streams ----------
__global__ __launch_bounds__(256) void k_prepW2(const float* __restrict__ pi,
    const float* __restrict__ pu, uint4* __restrict__ WfI, uint4* __restrict__ WfU) {
  __shared__ float tile[64][33];
  const float* src; uint4* wfrag; int NSRC, ks;
  if (blockIdx.x < NKI) { src = pi; wfrag = WfI; NSRC = NU; ks = blockIdx.x; }
  else                  { src = pu; wfrag = WfU; NSRC = NI; ks = blockIdx.x - NKI; }
  int tid = threadIdx.x;
  {
    int f = tid >> 2, part = tid & 3;
    int ubase = ks * 32 + part * 8;
    const float* sp = src + (size_t)f * NSRC;
#pragma unroll
    for (int q = 0; q < 8; q++) {
      int u = ubase + q;
      tile[f][part * 8 + q] = (u < NSRC) ? sp[u] : 0.f;
    }
  }
  __syncthreads();
  int l = tid & 63, t = tid >> 6;
  int g = l >> 4, f = t * 16 + (l & 15);
  int u0 = g * 8;
  uint32_t w[4];
#pragma unroll
  for (int p = 0; p < 4; p++) {
    __hip_bfloat16 blo = __float2bfloat16(tile[f][u0 + 2 * p]);
    __hip_bfloat16 bhi = __float2bfloat16(tile[f][u0 + 2 * p + 1]);
    w[p] = (uint32_t)*(uint16_t*)&blo | ((uint32_t)*(uint16_t*)&bhi << 16);
  }
  wfrag[(size_t)ks * 256 + tid] = make_uint4(w[0], w[1], w[2], w[3]);
}

// ---------- M: barrierless MFMA GEMM, M=32 rows/wave, item+user in one launch ----------
__global__ __launch_bounds__(256) void k_mfma2(
    const uint32_t* __restrict__ XallT, const uint32_t* __restrict__ Xall,
    const uint4* __restrict__ WfI, const uint4* __restrict__ WfU,
    const int* __restrict__ item_idx, const int* __restrict__ user_idx,
    float* __restrict__ partFI, float* __restrict__ partFU) {
  int lane = threadIdx.x & 63, wid = threadIdx.x >> 6;
  const uint32_t* bits; const uint4* wf; float* pf; const int* idx;
  int bstride, nk, seg, pair;
  if (blockIdx.x < 1024) {               // item: 32 pairs x 32 segs
    pair = blockIdx.x & 31; seg = blockIdx.x >> 5;
    bits = XallT; bstride = XTS; wf = WfI; pf = partFI; idx = item_idx; nk = NKI;
  } else {                               // user: 32 pairs x 16 segs
    int bx = blockIdx.x - 1024;
    pair = bx & 31; seg = bx >> 5;
    bits = Xall; bstride = XAS; wf = WfU; pf = partFU; idx = user_idx; nk = NKU;
  }
  int b0 = pair * 128 + wid * 32;
  int r0 = b0 + (lane & 15);
  int g = lane >> 4;
  int kbeg = seg * KCH, kend = min(nk, kbeg + KCH);
  const uint32_t* brow0 = bits + (size_t)idx[r0] * bstride;
  const uint32_t* brow1 = bits + (size_t)idx[r0 + 16] * bstride;
  f32x4 acc0[4] = {{0,0,0,0},{0,0,0,0},{0,0,0,0},{0,0,0,0}};
  f32x4 acc1[4] = {{0,0,0,0},{0,0,0,0},{0,0,0,0},{0,0,0,0}};
  for (int ks = kbeg; ks < kend; ++ks) {
    uint32_t by0 = (brow0[ks] >> (g * 8)) & 0xffu;
    uint32_t by1 = (brow1[ks] >> (g * 8)) & 0xffu;
    union { bf16x8 v; uint32_t u[4]; } A0, A1;
#pragma unroll
    for (int p = 0; p < 4; p++) {
      A0.u[p] = (((by0 >> (2 * p)) & 1u) ? 0x3F80u : 0u) |
                (((by0 >> (2 * p + 1)) & 1u) ? 0x3F800000u : 0u);
      A1.u[p] = (((by1 >> (2 * p)) & 1u) ? 0x3F80u : 0u) |
                (((by1 >> (2 * p + 1)) & 1u) ? 0x3F800000u : 0u);
    }
    const uint4* wp = wf + (size_t)ks * 256 + lane;
#pragma unroll
    for (int t = 0; t < 4; t++) {
      union { bf16x8 v; uint4 q; } Bf;
      Bf.q = wp[t * 64];
      acc0[t] = __builtin_amdgcn_mfma_f32_16x16x32_bf16(A0.v, Bf.v, acc0[t], 0, 0, 0);
      acc1[t] = __builtin_amdgcn_mfma_f32_16x16x32_bf16(A1.v, Bf.v, acc1[t], 0, 0, 0);
    }
  }
#pragma unroll
  for (int t = 0; t < 4; t++)
#pragma unroll
    for (int r = 0; r < 4; r++) {
      int b = b0 + (lane >> 4) * 4 + r;
      int f = t * 16 + (lane & 15);
      pf[((size_t)seg * B + b) * 64 + f] = acc0[t][r];
      pf[((size_t)seg * B + (b + 16)) * 64 + f] = acc1[t][r];
    }
}

// ---------- F: fused split-K reduce + popcount + mask-fix + normalize + embed + GMF ----------
__global__ __launch_bounds__(256) void k_final(
    const float* __restrict__ partFI, const float* __restrict__ partFU,
    const uint32_t* __restrict__ XallT, const uint32_t* __restrict__ Xall,
    const int* __restrict__ user_idx, const int* __restrict__ item_idx,
    const int* __restrict__ X, const float* __restrict__ pi, const float* __restrict__ pu,
    const float* __restrict__ uew, const float* __restrict__ iew,
    const float* __restrict__ lw, const float* __restrict__ lb,
    float* __restrict__ out) {
  int gid = blockIdx.x * 256 + threadIdx.x;
  int b = gid >> 6, f = gid & 63;
  int u = user_idx[b], it = item_idx[b];
  float ai = 0.f, au = 0.f;
  for (int s = 0; s < SPI; s++) ai += partFI[((size_t)s * B + b) * 64 + f];
  for (int s = 0; s < SPU; s++) au += partFU[((size_t)s * B + b) * 64 + f];
  const uint32_t* rowi = XallT + (size_t)it * XTS;
  const uint32_t* rowu = Xall + (size_t)u * XAS;
  int ci = 0, cu = 0;
  for (int d = f; d < NKI; d += 64) ci += __popc(rowi[d]);
  for (int d = f; d < NKU; d += 64) cu += __popc(rowu[d]);
  for (int off = 32; off; off >>= 1) {
    ci += __shfl_xor(ci, off);
    cu += __shfl_xor(cu, off);
  }
  int xc = X[(size_t)u * RS + it];
  if (xc) {
    ai -= pi[(size_t)f * NU + u];  ci -= 1;
    au -= pu[(size_t)f * NI + it]; cu -= 1;
  }
  float di = (float)ci; if (di < 1.f) di = 1.f;
  float du = (float)cu; if (du < 1.f) du = 1.f;
  float repi = iew[(size_t)it * 64 + f] + ai / sqrtf(di);
  float repu = uew[(size_t)u * 64 + f] + au / sqrtf(du);
  float v = repu * repi * lw[f];
  for (int off = 32; off; off >>= 1) v += __shfl_xor(v, off);
  if ((threadIdx.x & 63) == 0) out[b] = v + lb[0];
}

extern "C" void kernel_launch(void* const* d_in, const int* in_sizes, int n_in,
                              void* d_out, int out_size, void* d_ws, size_t ws_size,
                              hipStream_t stream) {
  const int*   user_idx = (const int*)d_in[0];
  const int*   item_idx = (const int*)d_in[1];
  const int*   X        = (const int*)d_in[2];
  const float* uew      = (const float*)d_in[3];
  const float* iew      = (const float*)d_in[4];
  const float* pu       = (const float*)d_in[5];   // (64, 10000)
  const float* pi       = (const float*)d_in[6];   // (64, 20000)
  const float* lw       = (const float*)d_in[7];
  const float* lb       = (const float*)d_in[8];
  float* out = (float*)d_out;

  char* wsb = (char*)d_ws;
  uint32_t* Xall   = (uint32_t*)(wsb + 0);             // 25,600,000
  uint32_t* XallT  = (uint32_t*)(wsb + 25600000);      // 26,214,400 (10240 x 2560B)
  uint4*    WfI    = (uint4*)(wsb + 51814400);         //  2,560,000
  uint4*    WfU    = (uint4*)(wsb + 54374400);         //  1,282,048
  float*    partFI = (float*)(wsb + 55656448);         // 33,554,432
  float*    partFU = (float*)(wsb + 89210880);         // 16,777,216
  uint32_t* Xflat  = (uint32_t*)partFI;                // 25,002,752 B, dead before mfma2

  k_prepW2<<<NKI + NKU, 256, 0, stream>>>(pi, pu, WfI, WfU);
  k_packflat<<<1024, 256, 0, stream>>>(X, Xflat);
  k_realign<<<25000, 256, 0, stream>>>(Xflat, Xall);
  k_bitT<<<dim3(20, 40), 256, 0, stream>>>(Xall, XallT);
  k_mfma2<<<1536, 256, 0, stream>>>(XallT, Xall, WfI, WfU, item_idx, user_idx,
                                    partFI, partFU);
  k_final<<<1024, 256, 0, stream>>>(partFI, partFU, XallT, Xall,
                                    user_idx, item_idx, X, pi, pu, uew, iew, lw, lb, out);
}

// Round 14
// 296.999 us; speedup vs baseline: 1.0423x; 1.0423x over previous
//
#include <hip/hip_runtime.h>
#include <hip/hip_bf16.h>
#include <stdint.h>

#define B    4096
#define NU   20000
#define NI   10000
#define RS   10001   // interactions row stride (ints)
#define XAS  320     // Xall row stride in dwords (10240 bits; 10000 used)
#define XTS  640     // XallT row stride in dwords (20480 bits; 20000 used)
#define NKI  625     // item K dwords (20000 bits)
#define NKU  313     // user K dwords (10000+16 pad bits)
#define SPI  16      // item split-K segments (kch 40)
#define SPU  16      // user split-K segments (kch 20)
#define KCHI 40
#define KCHU 20

typedef __attribute__((ext_vector_type(8))) short bf16x8;
typedef __attribute__((ext_vector_type(4))) float f32x4;

// ---------- P1: stream-pack X into bits (identity order) — R9-verified variant ----------
__global__ __launch_bounds__(256) void k_packall(const int* __restrict__ X,
                                                 uint32_t* __restrict__ Xall) {
  int lane = threadIdx.x & 63, wv = threadIdx.x >> 6;
  int u = blockIdx.x * 4 + wv;
  const int* row = X + (size_t)u * RS;
  uint32_t* dst = Xall + (size_t)u * XAS;
  if (lane < 7) dst[313 + lane] = 0u;        // pad words 313..319 for bitT u64 reads
  for (int it = 0; it < 40; ++it) {
    int c0 = it * 256 + lane * 4;
    int v0, v1, v2, v3;
    if (it < 39) {
      v0 = row[c0]; v1 = row[c0 + 1]; v2 = row[c0 + 2]; v3 = row[c0 + 3];
    } else {
      v0 = (c0     < NI) ? row[c0]     : 0;
      v1 = (c0 + 1 < NI) ? row[c0 + 1] : 0;
      v2 = (c0 + 2 < NI) ? row[c0 + 2] : 0;
      v3 = (c0 + 3 < NI) ? row[c0 + 3] : 0;
    }
    uint32_t nib = (v0 ? 1u : 0u) | (v1 ? 2u : 0u) | (v2 ? 4u : 0u) | (v3 ? 8u : 0u);
    uint32_t acc = nib << ((lane & 7) * 4);
    acc |= __shfl_xor(acc, 1);
    acc |= __shfl_xor(acc, 2);
    acc |= __shfl_xor(acc, 4);               // lanes 8g..8g+7 now all hold word g
    int k = it * 8 + (lane >> 3);
    if ((lane & 7) == 0 && k < 313) dst[k] = acc;
  }
}

// ---------- P2: bit transpose via register butterfly, coalesced via LDS ----------
__global__ __launch_bounds__(256) void k_bitT(const uint32_t* __restrict__ Xall,
                                              uint32_t* __restrict__ XallT) {
  __shared__ uint32_t ilo[512][9], ihi[512][9];   // odd stride -> conflict-free cols
  __shared__ uint32_t olo[512][9], ohi[512][9];
  int t = threadIdx.x;
  int lane = t & 63, wd = t >> 6;
  int W0 = blockIdx.x * 8;                   // u64-word group along j
  int u0 = blockIdx.y * 512;                 // u band
  int rr = t >> 3, w = t & 7;
  const unsigned long long* Xq = (const unsigned long long*)Xall;
  unsigned long long* Tq = (unsigned long long*)XallT;
  for (int i = 0; i < 16; ++i) {
    int r = rr + 32 * i;
    int u = u0 + r;
    unsigned long long v = (u < NU) ? Xq[(size_t)u * (XAS / 2) + W0 + w] : 0ULL;
    ilo[r][w] = (uint32_t)v;
    ihi[r][w] = (uint32_t)(v >> 32);
  }
  __syncthreads();
  const unsigned long long ML[6] = {
    0x5555555555555555ULL, 0x3333333333333333ULL, 0x0F0F0F0F0F0F0F0FULL,
    0x00FF00FF00FF00FFULL, 0x0000FFFF0000FFFFULL, 0x00000000FFFFFFFFULL };
  for (int i = 0; i < 16; ++i) {
    int tile = wd * 16 + i;
    int c = tile >> 3, W = tile & 7;
    int rowi = c * 64 + lane;
    unsigned long long x = ((unsigned long long)ihi[rowi][W] << 32) | ilo[rowi][W];
#pragma unroll
    for (int lv = 0; lv < 6; ++lv) {
      int s = 1 << lv;
      unsigned long long m = ML[lv];
      uint32_t xl = (uint32_t)x, xh = (uint32_t)(x >> 32);
      unsigned long long y = ((unsigned long long)__shfl_xor(xh, s) << 32) |
                             (uint32_t)__shfl_xor(xl, s);
      x = (lane & s) ? ((x & ~m) | ((y & ~m) >> s))
                     : ((x & m) | ((y & m) << s));
    }
    int rowo = W * 64 + lane;
    olo[rowo][c] = (uint32_t)x;
    ohi[rowo][c] = (uint32_t)(x >> 32);
  }
  __syncthreads();
  for (int i = 0; i < 16; ++i) {
    int r = rr + 32 * i;
    int j = W0 * 64 + r;
    unsigned long long v = ((unsigned long long)ohi[r][w] << 32) | olo[r][w];
    Tq[(size_t)j * (XTS / 2) + blockIdx.y * 8 + w] = v;
  }
}

// ---------- W: both weights -> per-lane-contiguous bf16 fragment streams ----------
__global__ __launch_bounds__(256) void k_prepW2(const float* __restrict__ pi,
    const float* __restrict__ pu, uint4* __restrict__ WfI, uint4* __restrict__ WfU) {
  __shared__ float tile[64][33];
  const float* src; uint4* wfrag; int NSRC, ks;
  if (blockIdx.x < NKI) { src = pi; wfrag = WfI; NSRC = NU; ks = blockIdx.x; }
  else                  { src = pu; wfrag = WfU; NSRC = NI; ks = blockIdx.x - NKI; }
  int tid = threadIdx.x;
  {
    int f = tid >> 2, part = tid & 3;
    int ubase = ks * 32 + part * 8;
    const float* sp = src + (size_t)f * NSRC;
#pragma unroll
    for (int q = 0; q < 8; q++) {
      int u = ubase + q;
      tile[f][part * 8 + q] = (u < NSRC) ? sp[u] : 0.f;
    }
  }
  __syncthreads();
  int l = tid & 63, t = tid >> 6;
  int g = l >> 4, f = t * 16 + (l & 15);
  int u0 = g * 8;
  uint32_t w[4];
#pragma unroll
  for (int p = 0; p < 4; p++) {
    __hip_bfloat16 blo = __float2bfloat16(tile[f][u0 + 2 * p]);
    __hip_bfloat16 bhi = __float2bfloat16(tile[f][u0 + 2 * p + 1]);
    w[p] = (uint32_t)*(uint16_t*)&blo | ((uint32_t)*(uint16_t*)&bhi << 16);
  }
  wfrag[(size_t)ks * 256 + tid] = make_uint4(w[0], w[1], w[2], w[3]);
}

// ---------- M: barrierless MFMA GEMM, M=32 rows/wave, item+user in one launch ----------
__global__ __launch_bounds__(256) void k_mfma2(
    const uint32_t* __restrict__ XallT, const uint32_t* __restrict__ Xall,
    const uint4* __restrict__ WfI, const uint4* __restrict__ WfU,
    const int* __restrict__ item_idx, const int* __restrict__ user_idx,
    float* __restrict__ partFI, float* __restrict__ partFU) {
  int lane = threadIdx.x & 63, wid = threadIdx.x >> 6;
  const uint32_t* bits; const uint4* wf; float* pf; const int* idx;
  int bstride, nk, seg, pair, kch;
  if (blockIdx.x < 512) {                // item: 32 pairs x 16 segs, kch 40
    pair = blockIdx.x & 31; seg = blockIdx.x >> 5;
    bits = XallT; bstride = XTS; wf = WfI; pf = partFI; idx = item_idx;
    nk = NKI; kch = KCHI;
  } else {                               // user: 32 pairs x 16 segs, kch 20
    int bx = blockIdx.x - 512;
    pair = bx & 31; seg = bx >> 5;
    bits = Xall; bstride = XAS; wf = WfU; pf = partFU; idx = user_idx;
    nk = NKU; kch = KCHU;
  }
  int b0 = pair * 128 + wid * 32;
  int r0 = b0 + (lane & 15);
  int g = lane >> 4;
  int kbeg = seg * kch, kend = min(nk, kbeg + kch);
  const uint32_t* brow0 = bits + (size_t)idx[r0] * bstride;
  const uint32_t* brow1 = bits + (size_t)idx[r0 + 16] * bstride;
  f32x4 acc0[4] = {{0,0,0,0},{0,0,0,0},{0,0,0,0},{0,0,0,0}};
  f32x4 acc1[4] = {{0,0,0,0},{0,0,0,0},{0,0,0,0},{0,0,0,0}};
  for (int ks = kbeg; ks < kend; ++ks) {
    uint32_t by0 = (brow0[ks] >> (g * 8)) & 0xffu;
    uint32_t by1 = (brow1[ks] >> (g * 8)) & 0xffu;
    union { bf16x8 v; uint32_t u[4]; } A0, A1;
#pragma unroll
    for (int p = 0; p < 4; p++) {
      A0.u[p] = (((by0 >> (2 * p)) & 1u) ? 0x3F80u : 0u) |
                (((by0 >> (2 * p + 1)) & 1u) ? 0x3F800000u : 0u);
      A1.u[p] = (((by1 >> (2 * p)) & 1u) ? 0x3F80u : 0u) |
                (((by1 >> (2 * p + 1)) & 1u) ? 0x3F800000u : 0u);
    }
    const uint4* wp = wf + (size_t)ks * 256 + lane;
#pragma unroll
    for (int t = 0; t < 4; t++) {
      union { bf16x8 v; uint4 q; } Bf;
      Bf.q = wp[t * 64];
      acc0[t] = __builtin_amdgcn_mfma_f32_16x16x32_bf16(A0.v, Bf.v, acc0[t], 0, 0, 0);
      acc1[t] = __builtin_amdgcn_mfma_f32_16x16x32_bf16(A1.v, Bf.v, acc1[t], 0, 0, 0);
    }
  }
#pragma unroll
  for (int t = 0; t < 4; t++)
#pragma unroll
    for (int r = 0; r < 4; r++) {
      int b = b0 + (lane >> 4) * 4 + r;
      int f = t * 16 + (lane & 15);
      pf[((size_t)seg * B + b) * 64 + f] = acc0[t][r];
      pf[((size_t)seg * B + (b + 16)) * 64 + f] = acc1[t][r];
    }
}

// ---------- F: fused split-K reduce + popcount + mask-fix + normalize + embed + GMF ----------
__global__ __launch_bounds__(256) void k_final(
    const float* __restrict__ partFI, const float* __restrict__ partFU,
    const uint32_t* __restrict__ XallT, const uint32_t* __restrict__ Xall,
    const int* __restrict__ user_idx, const int* __restrict__ item_idx,
    const int* __restrict__ X, const float* __restrict__ pi, const float* __restrict__ pu,
    const float* __restrict__ uew, const float* __restrict__ iew,
    const float* __restrict__ lw, const float* __restrict__ lb,
    float* __restrict__ out) {
  int gid = blockIdx.x * 256 + threadIdx.x;
  int b = gid >> 6, f = gid & 63;
  int u = user_idx[b], it = item_idx[b];
  float ai = 0.f, au = 0.f;
  for (int s = 0; s < SPI; s++) ai += partFI[((size_t)s * B + b) * 64 + f];
  for (int s = 0; s < SPU; s++) au += partFU[((size_t)s * B + b) * 64 + f];
  const uint32_t* rowi = XallT + (size_t)it * XTS;
  const uint32_t* rowu = Xall + (size_t)u * XAS;
  int ci = 0, cu = 0;
  for (int d = f; d < NKI; d += 64) ci += __popc(rowi[d]);
  for (int d = f; d < NKU; d += 64) cu += __popc(rowu[d]);
  for (int off = 32; off; off >>= 1) {
    ci += __shfl_xor(ci, off);
    cu += __shfl_xor(cu, off);
  }
  int xc = X[(size_t)u * RS + it];
  if (xc) {
    ai -= pi[(size_t)f * NU + u];  ci -= 1;
    au -= pu[(size_t)f * NI + it]; cu -= 1;
  }
  float di = (float)ci; if (di < 1.f) di = 1.f;
  float du = (float)cu; if (du < 1.f) du = 1.f;
  float repi = iew[(size_t)it * 64 + f] + ai / sqrtf(di);
  float repu = uew[(size_t)u * 64 + f] + au / sqrtf(du);
  float v = repu * repi * lw[f];
  for (int off = 32; off; off >>= 1) v += __shfl_xor(v, off);
  if ((threadIdx.x & 63) == 0) out[b] = v + lb[0];
}

extern "C" void kernel_launch(void* const* d_in, const int* in_sizes, int n_in,
                              void* d_out, int out_size, void* d_ws, size_t ws_size,
                              hipStream_t stream) {
  const int*   user_idx = (const int*)d_in[0];
  const int*   item_idx = (const int*)d_in[1];
  const int*   X        = (const int*)d_in[2];
  const float* uew      = (const float*)d_in[3];
  const float* iew      = (const float*)d_in[4];
  const float* pu       = (const float*)d_in[5];   // (64, 10000)
  const float* pi       = (const float*)d_in[6];   // (64, 20000)
  const float* lw       = (const float*)d_in[7];
  const float* lb       = (const float*)d_in[8];
  float* out = (float*)d_out;

  char* wsb = (char*)d_ws;
  uint32_t* Xall   = (uint32_t*)(wsb + 0);             // 25,600,000
  uint32_t* XallT  = (uint32_t*)(wsb + 25600000);      // 26,214,400 (10240 x 2560B)
  uint4*    WfI    = (uint4*)(wsb + 51814400);         //  2,560,000
  uint4*    WfU    = (uint4*)(wsb + 54374400);         //  1,282,048
  float*    partFI = (float*)(wsb + 55656448);         // 16,777,216
  float*    partFU = (float*)(wsb + 72433664);         // 16,777,216

  k_prepW2<<<NKI + NKU, 256, 0, stream>>>(pi, pu, WfI, WfU);
  k_packall<<<5000, 256, 0, stream>>>(X, Xall);
  k_bitT<<<dim3(20, 40), 256, 0, stream>>>(Xall, XallT);
  k_mfma2<<<1024, 256, 0, stream>>>(XallT, Xall, WfI, WfU, item_idx, user_idx,
                                    partFI, partFU);
  k_final<<<1024, 256, 0, stream>>>(partFI, partFU, XallT, Xall,
                                    user_idx, item_idx, X, pi, pu, uew, iew, lw, lb, out);
}